// Round 1
// baseline (374.470 us; speedup 1.0000x reference)
//
#include <hip/hip_runtime.h>

#define S_LEN 2048
#define DIMSZ 3072
#define NHEAD 24
#define HDIM 128
#define NQKV 9216
#define QSCALE 0.08838834764831845f

typedef unsigned short u16;
typedef unsigned int u32;
typedef __attribute__((ext_vector_type(8))) short short8;
typedef __attribute__((ext_vector_type(4))) float f32x4;

__device__ __forceinline__ u16 f2bf(float f) {
    u32 u = __float_as_uint(f);
    u32 r = (u + 0x7fffu + ((u >> 16) & 1u)) >> 16;
    return (u16)r;
}

__device__ __forceinline__ void lds16(u16* lds, const u16* g) {
    __builtin_amdgcn_global_load_lds((const __attribute__((address_space(1))) u32*)g,
                                     (__attribute__((address_space(3))) u32*)lds, 16, 0, 0);
}

// ---------------- conversion kernels ----------------
__global__ void k_f2bf4(const float4* __restrict__ src, u16* __restrict__ dst, int n4) {
    int i = blockIdx.x * blockDim.x + threadIdx.x;
    if (i >= n4) return;
    float4 v = src[i];
    u32 lo = (u32)f2bf(v.x) | ((u32)f2bf(v.y) << 16);
    u32 hi = (u32)f2bf(v.z) | ((u32)f2bf(v.w) << 16);
    uint2 p; p.x = lo; p.y = hi;
    *(uint2*)(dst + (size_t)i * 4) = p;
}

__global__ void k_bias(const float* __restrict__ bq, const float* __restrict__ bk,
                       const float* __restrict__ bv, float* __restrict__ bias) {
    int i = blockIdx.x * 256 + threadIdx.x;
    if (i < 3072) bias[i] = bq[i];
    else if (i < 6144) bias[i] = bk[i - 3072];
    else if (i < 9216) bias[i] = bv[i - 6144];
}

// ---------------- QKV GEMM: C[m][n] = sum_k A[m][k]*W[n][k] + bias[n] ----------------
// A: [2048][3072] bf16, W: [9216][3072] bf16, C: [2048][9216] f32
__global__ __launch_bounds__(256, 2) void k_gemm(const u16* __restrict__ A, const u16* __restrict__ W,
                                                 const float* __restrict__ bias, float* __restrict__ C) {
    __shared__ __align__(16) u16 As[128 * 64];
    __shared__ __align__(16) u16 Bs[128 * 64];
    const int bn = blockIdx.x, bm = blockIdx.y;
    const int tid = threadIdx.x, wave = tid >> 6, lane = tid & 63;
    const int frow = lane & 15, fk = lane >> 4;
    const int wr = wave >> 1, wc = wave & 1;
    f32x4 acc[4][4] = {};

    for (int kt = 0; kt < DIMSZ / 64; ++kt) {
#pragma unroll
        for (int c = 0; c < 4; ++c) {
            int fi = (wave * 4 + c) * 64 + lane;
            int r = fi >> 3, ch = fi & 7;
            lds16(As + (wave * 4 + c) * 512,
                  A + (size_t)(bm * 128 + r) * DIMSZ + kt * 64 + ch * 8);
            lds16(Bs + (wave * 4 + c) * 512,
                  W + (size_t)(bn * 128 + r) * DIMSZ + kt * 64 + ch * 8);
        }
        __syncthreads();
#pragma unroll
        for (int ks = 0; ks < 2; ++ks) {
            short8 af[4], bfr[4];
#pragma unroll
            for (int mf = 0; mf < 4; ++mf)
                af[mf] = *(const short8*)&As[(wr * 64 + mf * 16 + frow) * 64 + ks * 32 + fk * 8];
#pragma unroll
            for (int nf = 0; nf < 4; ++nf)
                bfr[nf] = *(const short8*)&Bs[(wc * 64 + nf * 16 + frow) * 64 + ks * 32 + fk * 8];
#pragma unroll
            for (int mf = 0; mf < 4; ++mf)
#pragma unroll
                for (int nf = 0; nf < 4; ++nf)
                    acc[mf][nf] = __builtin_amdgcn_mfma_f32_16x16x32_bf16(af[mf], bfr[nf], acc[mf][nf], 0, 0, 0);
        }
        __syncthreads();
    }
#pragma unroll
    for (int mf = 0; mf < 4; ++mf) {
#pragma unroll
        for (int nf = 0; nf < 4; ++nf) {
            int n = bn * 128 + wc * 64 + nf * 16 + frow;
            float b = bias[n];
#pragma unroll
            for (int i = 0; i < 4; ++i) {
                int m = bm * 128 + wr * 64 + mf * 16 + fk * 4 + i;
                C[(size_t)m * NQKV + n] = acc[mf][nf][i] + b;
            }
        }
    }
}

// ---------------- postprocess: RMSNorm + RoPE + layout ----------------
// qkv: [2048][9216] f32. Writes Qb,Kb: [24][2048][128] bf16 (Q scaled by 1/sqrt(D)), Vt: [24][128][2048] bf16
__global__ void k_post(const float* __restrict__ qkv, const float* __restrict__ nw_q,
                       const float* __restrict__ nw_k, const float* __restrict__ cosT,
                       const float* __restrict__ sinT, u16* __restrict__ Qb,
                       u16* __restrict__ Kb, u16* __restrict__ Vt) {
    const int wave = threadIdx.x >> 6, lane = threadIdx.x & 63;
    const int s = blockIdx.x * 4 + wave;
    const int h = blockIdx.y;
    const int d0 = 2 * lane, d1 = 2 * lane + 1;
    const float c = cosT[s * HDIM + d0], sn = sinT[s * HDIM + d0];
    // Q
    {
        const float* row = qkv + (size_t)s * NQKV + h * HDIM;
        float x0 = row[d0], x1 = row[d1];
        float ss = x0 * x0 + x1 * x1;
        for (int m = 1; m < 64; m <<= 1) ss += __shfl_xor(ss, m);
        float r = rsqrtf(ss * (1.0f / 128.0f) + 1e-6f);
        x0 *= r * nw_q[d0]; x1 *= r * nw_q[d1];
        float o0 = (x0 * c - x1 * sn) * QSCALE;
        float o1 = (x1 * c + x0 * sn) * QSCALE;
        u32 p = (u32)f2bf(o0) | ((u32)f2bf(o1) << 16);
        *(u32*)&Qb[((size_t)h * S_LEN + s) * HDIM + d0] = p;
    }
    // K
    {
        const float* row = qkv + (size_t)s * NQKV + 3072 + h * HDIM;
        float x0 = row[d0], x1 = row[d1];
        float ss = x0 * x0 + x1 * x1;
        for (int m = 1; m < 64; m <<= 1) ss += __shfl_xor(ss, m);
        float r = rsqrtf(ss * (1.0f / 128.0f) + 1e-6f);
        x0 *= r * nw_k[d0]; x1 *= r * nw_k[d1];
        float o0 = x0 * c - x1 * sn;
        float o1 = x1 * c + x0 * sn;
        u32 p = (u32)f2bf(o0) | ((u32)f2bf(o1) << 16);
        *(u32*)&Kb[((size_t)h * S_LEN + s) * HDIM + d0] = p;
    }
    // V (transposed)
    {
        const float* row = qkv + (size_t)s * NQKV + 6144 + h * HDIM;
        Vt[((size_t)h * HDIM + d0) * S_LEN + s] = f2bf(row[d0]);
        Vt[((size_t)h * HDIM + d1) * S_LEN + s] = f2bf(row[d1]);
    }
}

// ---------------- flash attention (no mask) ----------------
// Qb,Kb: [24][2048][128] bf16, Vt: [24][128][2048] bf16, out: [2048][3072] f32
__global__ __launch_bounds__(256, 2) void k_attn(const u16* __restrict__ Qb, const u16* __restrict__ Kb,
                                                 const u16* __restrict__ Vt, float* __restrict__ out) {
    __shared__ __align__(16) u16 Ks[64 * 128];   // [key][d], chunk-swizzled: chunk ^= row&15
    __shared__ __align__(16) u16 Vs[128 * 64];   // [d][key], chunk-swizzled: chunk ^= row&7
    __shared__ __align__(16) u16 Ps[4][16 * 64]; // per-wave P, chunk-swizzled: chunk ^= row&7
    const int wave = threadIdx.x >> 6, lane = threadIdx.x & 63;
    const int h = blockIdx.y, qb = blockIdx.x;
    const int frow = lane & 15, fk = lane >> 4;

    short8 qf[4];
    const u16* qbase = Qb + ((size_t)h * S_LEN + qb * 64 + wave * 16 + frow) * HDIM + fk * 8;
#pragma unroll
    for (int ks = 0; ks < 4; ++ks) qf[ks] = *(const short8*)(qbase + ks * 32);

    f32x4 o[8] = {};
    float m_i[4], l_i[4];
#pragma unroll
    for (int i = 0; i < 4; ++i) { m_i[i] = -1e30f; l_i[i] = 0.f; }

    for (int kt = 0; kt < S_LEN / 64; ++kt) {
#pragma unroll
        for (int c = 0; c < 4; ++c) {
            int fi = (wave * 4 + c) * 64 + lane;
            {   // K tile: [64][128], 16 chunks/row; source pre-swizzled by row&15
                int r = fi >> 4, ch = fi & 15;
                lds16(Ks + (wave * 4 + c) * 512,
                      Kb + ((size_t)h * S_LEN + kt * 64 + r) * HDIM + ((ch ^ (r & 15)) * 8));
            }
            {   // V tile: [128][64], 8 chunks/row; source pre-swizzled by row&7
                int r = fi >> 3, ch = fi & 7;
                lds16(Vs + (wave * 4 + c) * 512,
                      Vt + ((size_t)h * HDIM + r) * S_LEN + kt * 64 + ((ch ^ (r & 7)) * 8));
            }
        }
        __syncthreads();
        // S = Q K^T  (16 q-rows x 64 keys per wave)
        f32x4 sacc[4] = {};
#pragma unroll
        for (int nf = 0; nf < 4; ++nf) {
#pragma unroll
            for (int ks = 0; ks < 4; ++ks) {
                short8 kf = *(const short8*)&Ks[(nf * 16 + frow) * 128 + (((ks * 4 + fk) ^ frow) & 15) * 8];
                sacc[nf] = __builtin_amdgcn_mfma_f32_16x16x32_bf16(qf[ks], kf, sacc[nf], 0, 0, 0);
            }
        }
        // online softmax
        float pm[4];
#pragma unroll
        for (int i = 0; i < 4; ++i)
            pm[i] = fmaxf(fmaxf(sacc[0][i], sacc[1][i]), fmaxf(sacc[2][i], sacc[3][i]));
#pragma unroll
        for (int msk = 1; msk < 16; msk <<= 1)
#pragma unroll
            for (int i = 0; i < 4; ++i) pm[i] = fmaxf(pm[i], __shfl_xor(pm[i], msk));
        float alpha[4], rs[4];
#pragma unroll
        for (int i = 0; i < 4; ++i) {
            float mn = fmaxf(m_i[i], pm[i]);
            alpha[i] = __expf(m_i[i] - mn);
            m_i[i] = mn;
            rs[i] = 0.f;
        }
#pragma unroll
        for (int nf = 0; nf < 4; ++nf) {
#pragma unroll
            for (int i = 0; i < 4; ++i) {
                float p = __expf(sacc[nf][i] - m_i[i]);
                rs[i] += p;
                int row = fk * 4 + i, col = nf * 16 + frow;
                Ps[wave][row * 64 + (((col >> 3) ^ (row & 7)) << 3) + (col & 7)] = f2bf(p);
            }
        }
#pragma unroll
        for (int msk = 1; msk < 16; msk <<= 1)
#pragma unroll
            for (int i = 0; i < 4; ++i) rs[i] += __shfl_xor(rs[i], msk);
#pragma unroll
        for (int i = 0; i < 4; ++i) l_i[i] = l_i[i] * alpha[i] + rs[i];
#pragma unroll
        for (int nf8 = 0; nf8 < 8; ++nf8)
#pragma unroll
            for (int i = 0; i < 4; ++i) o[nf8][i] *= alpha[i];
        // O += P V
#pragma unroll
        for (int ks = 0; ks < 2; ++ks) {
            short8 pf = *(const short8*)&Ps[wave][frow * 64 + (((ks * 4 + fk) ^ (frow & 7)) & 7) * 8];
#pragma unroll
            for (int nf8 = 0; nf8 < 8; ++nf8) {
                short8 vf = *(const short8*)&Vs[(nf8 * 16 + frow) * 64 + (((ks * 4 + fk) ^ (frow & 7)) & 7) * 8];
                o[nf8] = __builtin_amdgcn_mfma_f32_16x16x32_bf16(pf, vf, o[nf8], 0, 0, 0);
            }
        }
        __syncthreads();
    }
#pragma unroll
    for (int nf8 = 0; nf8 < 8; ++nf8)
#pragma unroll
        for (int i = 0; i < 4; ++i) {
            int srow = qb * 64 + wave * 16 + fk * 4 + i;
            out[(size_t)srow * DIMSZ + h * HDIM + nf8 * 16 + frow] = o[nf8][i] / l_i[i];
        }
}

// ---------------- launch ----------------
extern "C" void kernel_launch(void* const* d_in, const int* in_sizes, int n_in,
                              void* d_out, int out_size, void* d_ws, size_t ws_size,
                              hipStream_t stream) {
    const float* hs = (const float*)d_in[0];
    const float* wq = (const float*)d_in[1];
    const float* bq = (const float*)d_in[2];
    const float* wk = (const float*)d_in[3];
    const float* bk = (const float*)d_in[4];
    const float* wv = (const float*)d_in[5];
    const float* bv = (const float*)d_in[6];
    const float* nq = (const float*)d_in[7];
    const float* nk = (const float*)d_in[8];
    const float* cosT = (const float*)d_in[9];
    const float* sinT = (const float*)d_in[10];
    float* out = (float*)d_out;

    char* ws = (char*)d_ws;
    u16* hs_b = (u16*)(ws + 0);                  // 12,582,912 B
    u16* w_b = (u16*)(ws + 12582912);            // 56,623,104 B
    float* bias = (float*)(ws + 69206016);       // 36,864 B
    float* qkv = (float*)(ws + 69242880);        // 75,497,472 B
    u16* Qb = (u16*)(ws + 144740352);            // 12,582,912 B
    u16* Kb = (u16*)(ws + 157323264);            // 12,582,912 B
    u16* Vt = (u16*)(ws + 169906176);            // 12,582,912 B -> total 182,489,088 B

    // convert hs + weights to bf16
    k_f2bf4<<<6144, 256, 0, stream>>>((const float4*)hs, hs_b, 1572864);
    k_f2bf4<<<9216, 256, 0, stream>>>((const float4*)wq, w_b, 2359296);
    k_f2bf4<<<9216, 256, 0, stream>>>((const float4*)wk, w_b + 9437184, 2359296);
    k_f2bf4<<<9216, 256, 0, stream>>>((const float4*)wv, w_b + 18874368, 2359296);
    k_bias<<<36, 256, 0, stream>>>(bq, bk, bv, bias);

    // QKV projection
    k_gemm<<<dim3(72, 16), 256, 0, stream>>>(hs_b, w_b, bias, qkv);

    // RMSNorm + RoPE + relayout
    k_post<<<dim3(512, 24), 256, 0, stream>>>(qkv, nq, nk, cosT, sinT, Qb, Kb, Vt);

    // attention
    k_attn<<<dim3(32, 24), 256, 0, stream>>>(Qb, Kb, Vt, out);
}

// Round 2
// 345.304 us; speedup vs baseline: 1.0845x; 1.0845x over previous
//
#include <hip/hip_runtime.h>

#define S_LEN 2048
#define DIMSZ 3072
#define NHEAD 24
#define HDIM 128
#define NQKV 9216
#define QSCALE 0.08838834764831845f
#define FMAX 12.0f

typedef unsigned short u16;
typedef unsigned int u32;
typedef __attribute__((ext_vector_type(8))) short short8;
typedef __attribute__((ext_vector_type(4))) float f32x4;

__device__ __forceinline__ u16 f2bf(float f) {
    u32 u = __float_as_uint(f);
    u32 r = (u + 0x7fffu + ((u >> 16) & 1u)) >> 16;
    return (u16)r;
}

__device__ __forceinline__ void lds16(u16* lds, const u16* g) {
    __builtin_amdgcn_global_load_lds((const __attribute__((address_space(1))) u32*)g,
                                     (__attribute__((address_space(3))) u32*)lds, 16, 0, 0);
}

// ---------------- conversion kernels ----------------
__global__ void k_f2bf4(const float4* __restrict__ src, u16* __restrict__ dst, int n4) {
    int i = blockIdx.x * blockDim.x + threadIdx.x;
    if (i >= n4) return;
    float4 v = src[i];
    u32 lo = (u32)f2bf(v.x) | ((u32)f2bf(v.y) << 16);
    u32 hi = (u32)f2bf(v.z) | ((u32)f2bf(v.w) << 16);
    uint2 p; p.x = lo; p.y = hi;
    *(uint2*)(dst + (size_t)i * 4) = p;
}

__global__ void k_bias(const float* __restrict__ bq, const float* __restrict__ bk,
                       const float* __restrict__ bv, float* __restrict__ bias) {
    int i = blockIdx.x * 256 + threadIdx.x;
    if (i < 3072) bias[i] = bq[i];
    else if (i < 6144) bias[i] = bk[i - 3072];
    else if (i < 9216) bias[i] = bv[i - 6144];
}

// ---------------- QKV GEMM: C[m][n] = sum_k A[m][k]*W[n][k] + bias[n] ----------------
__global__ __launch_bounds__(256, 2) void k_gemm(const u16* __restrict__ A, const u16* __restrict__ W,
                                                 const float* __restrict__ bias, float* __restrict__ C) {
    __shared__ __align__(16) u16 As[128 * 64];
    __shared__ __align__(16) u16 Bs[128 * 64];
    const int bn = blockIdx.x, bm = blockIdx.y;
    const int tid = threadIdx.x, wave = tid >> 6, lane = tid & 63;
    const int frow = lane & 15, fk = lane >> 4;
    const int wr = wave >> 1, wc = wave & 1;
    f32x4 acc[4][4] = {};

    for (int kt = 0; kt < DIMSZ / 64; ++kt) {
#pragma unroll
        for (int c = 0; c < 4; ++c) {
            int fi = (wave * 4 + c) * 64 + lane;
            int r = fi >> 3, ch = fi & 7;
            lds16(As + (wave * 4 + c) * 512,
                  A + (size_t)(bm * 128 + r) * DIMSZ + kt * 64 + ch * 8);
            lds16(Bs + (wave * 4 + c) * 512,
                  W + (size_t)(bn * 128 + r) * DIMSZ + kt * 64 + ch * 8);
        }
        __syncthreads();
#pragma unroll
        for (int ks = 0; ks < 2; ++ks) {
            short8 af[4], bfr[4];
#pragma unroll
            for (int mf = 0; mf < 4; ++mf)
                af[mf] = *(const short8*)&As[(wr * 64 + mf * 16 + frow) * 64 + ks * 32 + fk * 8];
#pragma unroll
            for (int nf = 0; nf < 4; ++nf)
                bfr[nf] = *(const short8*)&Bs[(wc * 64 + nf * 16 + frow) * 64 + ks * 32 + fk * 8];
#pragma unroll
            for (int mf = 0; mf < 4; ++mf)
#pragma unroll
                for (int nf = 0; nf < 4; ++nf)
                    acc[mf][nf] = __builtin_amdgcn_mfma_f32_16x16x32_bf16(af[mf], bfr[nf], acc[mf][nf], 0, 0, 0);
        }
        __syncthreads();
    }
#pragma unroll
    for (int mf = 0; mf < 4; ++mf) {
#pragma unroll
        for (int nf = 0; nf < 4; ++nf) {
            int n = bn * 128 + wc * 64 + nf * 16 + frow;
            float b = bias[n];
#pragma unroll
            for (int i = 0; i < 4; ++i) {
                int m = bm * 128 + wr * 64 + mf * 16 + fk * 4 + i;
                C[(size_t)m * NQKV + n] = acc[mf][nf][i] + b;
            }
        }
    }
}

// ---------------- postprocess: RMSNorm + RoPE + layout ----------------
__global__ void k_post(const float* __restrict__ qkv, const float* __restrict__ nw_q,
                       const float* __restrict__ nw_k, const float* __restrict__ cosT,
                       const float* __restrict__ sinT, u16* __restrict__ Qb,
                       u16* __restrict__ Kb, u16* __restrict__ Vt) {
    const int wave = threadIdx.x >> 6, lane = threadIdx.x & 63;
    const int s = blockIdx.x * 4 + wave;
    const int h = blockIdx.y;
    const int d0 = 2 * lane, d1 = 2 * lane + 1;
    const float c = cosT[s * HDIM + d0], sn = sinT[s * HDIM + d0];
    // Q
    {
        const float* row = qkv + (size_t)s * NQKV + h * HDIM;
        float x0 = row[d0], x1 = row[d1];
        float ss = x0 * x0 + x1 * x1;
        for (int m = 1; m < 64; m <<= 1) ss += __shfl_xor(ss, m);
        float r = rsqrtf(ss * (1.0f / 128.0f) + 1e-6f);
        x0 *= r * nw_q[d0]; x1 *= r * nw_q[d1];
        float o0 = (x0 * c - x1 * sn) * QSCALE;
        float o1 = (x1 * c + x0 * sn) * QSCALE;
        u32 p = (u32)f2bf(o0) | ((u32)f2bf(o1) << 16);
        *(u32*)&Qb[((size_t)h * S_LEN + s) * HDIM + d0] = p;
    }
    // K
    {
        const float* row = qkv + (size_t)s * NQKV + 3072 + h * HDIM;
        float x0 = row[d0], x1 = row[d1];
        float ss = x0 * x0 + x1 * x1;
        for (int m = 1; m < 64; m <<= 1) ss += __shfl_xor(ss, m);
        float r = rsqrtf(ss * (1.0f / 128.0f) + 1e-6f);
        x0 *= r * nw_k[d0]; x1 *= r * nw_k[d1];
        float o0 = x0 * c - x1 * sn;
        float o1 = x1 * c + x0 * sn;
        u32 p = (u32)f2bf(o0) | ((u32)f2bf(o1) << 16);
        *(u32*)&Kb[((size_t)h * S_LEN + s) * HDIM + d0] = p;
    }
    // V (transposed)
    {
        const float* row = qkv + (size_t)s * NQKV + 6144 + h * HDIM;
        Vt[((size_t)h * HDIM + d0) * S_LEN + s] = f2bf(row[d0]);
        Vt[((size_t)h * HDIM + d1) * S_LEN + s] = f2bf(row[d1]);
    }
}

// ---------------- flash attention (no mask, fixed-max softmax) ----------------
// Qb,Kb: [24][2048][128] bf16 (Q pre-scaled by 1/sqrt(D)), Vt: [24][128][2048] bf16, out: [2048][3072] f32
// 4 waves/block, 32 q-rows/wave (128/block), KVBLK=64, double-buffered K/V LDS.
// |score| <= ||q||*||k||*scale = sqrt(128) < 12  =>  p = exp(s - 12), no online rescale needed.
__global__ __launch_bounds__(256, 2) void k_attn(const u16* __restrict__ Qb, const u16* __restrict__ Kb,
                                                 const u16* __restrict__ Vt, float* __restrict__ out) {
    __shared__ __align__(16) u16 Ks[2][64 * 128];   // [key][d], chunk ^= row&15
    __shared__ __align__(16) u16 Vs[2][128 * 64];   // [d][key], chunk ^= row&7
    __shared__ __align__(16) u16 Ps[4][32 * 64];    // per-wave P, chunk ^= row&7
    const int wave = threadIdx.x >> 6, lane = threadIdx.x & 63;
    // XCD-bijective swizzle: 384 blocks = 8 XCDs x 48 (= 3 heads of 16 q-blocks each)
    const int wg = (blockIdx.x & 7) * 48 + (blockIdx.x >> 3);
    const int h = wg >> 4, qb = wg & 15;
    const int frow = lane & 15, fk = lane >> 4;

    // Q fragments: 2 groups of 16 rows
    short8 qf[2][4];
#pragma unroll
    for (int qg = 0; qg < 2; ++qg) {
        const u16* qbase = Qb + ((size_t)h * S_LEN + qb * 128 + wave * 32 + qg * 16 + frow) * HDIM + fk * 8;
#pragma unroll
        for (int ks = 0; ks < 4; ++ks) qf[qg][ks] = *(const short8*)(qbase + ks * 32);
    }

    f32x4 o[2][8] = {};
    float l_p[2][4] = {};

#define STAGE(buf, kt)                                                                       \
    {                                                                                        \
        _Pragma("unroll") for (int c = 0; c < 4; ++c) {                                      \
            int fi = (wave * 4 + c) * 64 + lane;                                             \
            {                                                                                \
                int r = fi >> 4, ch = fi & 15;                                               \
                lds16(Ks[buf] + (wave * 4 + c) * 512,                                        \
                      Kb + ((size_t)h * S_LEN + (kt) * 64 + r) * HDIM + ((ch ^ (r & 15)) * 8)); \
            }                                                                                \
            {                                                                                \
                int r = fi >> 3, ch = fi & 7;                                                \
                lds16(Vs[buf] + (wave * 4 + c) * 512,                                        \
                      Vt + ((size_t)h * HDIM + r) * S_LEN + (kt) * 64 + ((ch ^ (r & 7)) * 8)); \
            }                                                                                \
        }                                                                                    \
    }

    STAGE(0, 0);
    __syncthreads();
    int cur = 0;

    for (int kt = 0; kt < S_LEN / 64; ++kt) {
        if (kt + 1 < S_LEN / 64) STAGE(cur ^ 1, kt + 1);
        // S = Q K^T : 32 q-rows x 64 keys per wave
        f32x4 sacc[2][4] = {};
#pragma unroll
        for (int nf = 0; nf < 4; ++nf) {
#pragma unroll
            for (int ks = 0; ks < 4; ++ks) {
                short8 kf = *(const short8*)&Ks[cur][(nf * 16 + frow) * 128 + (((ks * 4 + fk) ^ frow) & 15) * 8];
#pragma unroll
                for (int qg = 0; qg < 2; ++qg)
                    sacc[qg][nf] = __builtin_amdgcn_mfma_f32_16x16x32_bf16(qf[qg][ks], kf, sacc[qg][nf], 0, 0, 0);
            }
        }
        // fixed-max softmax: p = exp(s - 12), accumulate l in-lane, stage P to LDS
#pragma unroll
        for (int qg = 0; qg < 2; ++qg)
#pragma unroll
            for (int nf = 0; nf < 4; ++nf)
#pragma unroll
                for (int i = 0; i < 4; ++i) {
                    float p = __expf(sacc[qg][nf][i] - FMAX);
                    l_p[qg][i] += p;
                    int row = qg * 16 + fk * 4 + i, col = nf * 16 + frow;
                    Ps[wave][row * 64 + (((col >> 3) ^ (row & 7)) << 3) + (col & 7)] = f2bf(p);
                }
        // O += P V
#pragma unroll
        for (int ks = 0; ks < 2; ++ks) {
            short8 pf[2];
#pragma unroll
            for (int qg = 0; qg < 2; ++qg)
                pf[qg] = *(const short8*)&Ps[wave][(qg * 16 + frow) * 64 + (((ks * 4 + fk) ^ (frow & 7)) & 7) * 8];
#pragma unroll
            for (int nf8 = 0; nf8 < 8; ++nf8) {
                short8 vf = *(const short8*)&Vs[cur][(nf8 * 16 + frow) * 64 + (((ks * 4 + fk) ^ (frow & 7)) & 7) * 8];
#pragma unroll
                for (int qg = 0; qg < 2; ++qg)
                    o[qg][nf8] = __builtin_amdgcn_mfma_f32_16x16x32_bf16(pf[qg], vf, o[qg][nf8], 0, 0, 0);
            }
        }
        __syncthreads();
        cur ^= 1;
    }
#undef STAGE

    // final l reduction across the 16-lane frow groups
#pragma unroll
    for (int msk = 1; msk < 16; msk <<= 1)
#pragma unroll
        for (int qg = 0; qg < 2; ++qg)
#pragma unroll
            for (int i = 0; i < 4; ++i) l_p[qg][i] += __shfl_xor(l_p[qg][i], msk);

#pragma unroll
    for (int qg = 0; qg < 2; ++qg)
#pragma unroll
        for (int nf8 = 0; nf8 < 8; ++nf8)
#pragma unroll
            for (int i = 0; i < 4; ++i) {
                int srow = qb * 128 + wave * 32 + qg * 16 + fk * 4 + i;
                out[(size_t)srow * DIMSZ + h * HDIM + nf8 * 16 + frow] = o[qg][nf8][i] / l_p[qg][i];
            }
}

// ---------------- launch ----------------
extern "C" void kernel_launch(void* const* d_in, const int* in_sizes, int n_in,
                              void* d_out, int out_size, void* d_ws, size_t ws_size,
                              hipStream_t stream) {
    const float* hs = (const float*)d_in[0];
    const float* wq = (const float*)d_in[1];
    const float* bq = (const float*)d_in[2];
    const float* wk = (const float*)d_in[3];
    const float* bk = (const float*)d_in[4];
    const float* wv = (const float*)d_in[5];
    const float* bv = (const float*)d_in[6];
    const float* nq = (const float*)d_in[7];
    const float* nk = (const float*)d_in[8];
    const float* cosT = (const float*)d_in[9];
    const float* sinT = (const float*)d_in[10];
    float* out = (float*)d_out;

    char* ws = (char*)d_ws;
    u16* hs_b = (u16*)(ws + 0);                  // 12,582,912 B
    u16* w_b = (u16*)(ws + 12582912);            // 56,623,104 B
    float* bias = (float*)(ws + 69206016);       // 36,864 B
    float* qkv = (float*)(ws + 69242880);        // 75,497,472 B
    u16* Qb = (u16*)(ws + 144740352);            // 12,582,912 B
    u16* Kb = (u16*)(ws + 157323264);            // 12,582,912 B
    u16* Vt = (u16*)(ws + 169906176);            // 12,582,912 B -> total 182,489,088 B

    // convert hs + weights to bf16
    k_f2bf4<<<6144, 256, 0, stream>>>((const float4*)hs, hs_b, 1572864);
    k_f2bf4<<<9216, 256, 0, stream>>>((const float4*)wq, w_b, 2359296);
    k_f2bf4<<<9216, 256, 0, stream>>>((const float4*)wk, w_b + 9437184, 2359296);
    k_f2bf4<<<9216, 256, 0, stream>>>((const float4*)wv, w_b + 18874368, 2359296);
    k_bias<<<36, 256, 0, stream>>>(bq, bk, bv, bias);

    // QKV projection
    k_gemm<<<dim3(72, 16), 256, 0, stream>>>(hs_b, w_b, bias, qkv);

    // RMSNorm + RoPE + relayout
    k_post<<<dim3(512, 24), 256, 0, stream>>>(qkv, nq, nk, cosT, sinT, Qb, Kb, Vt);

    // attention: 384 blocks (16 q-blocks x 24 heads), XCD-swizzled
    k_attn<<<dim3(384), 256, 0, stream>>>(Qb, Kb, Vt, out);
}